// Round 1
// baseline (42.349 us; speedup 1.0000x reference)
//
#include <hip/hip_runtime.h>

// Problem constants
#define B_ 4096
#define S_ 32
#define K_ 1024
#define D_ 128
constexpr float DECAY = 0.99f;
constexpr float OMD   = 1.0f - 0.99f;   // 1 - decay
constexpr float EPS   = 1e-5f;

// ws layout: [0, S_*K_) int counts ; [S_*K_, 2*S_*K_) float cluster_size

// Kernel 1: fused z_q gather + histogram.
// One (b,s) row handled by 32 threads (32 x float4 = 128 floats).
// block = 256 threads -> 8 rows/block.
__global__ void __launch_bounds__(256)
gather_hist_kernel(const int* __restrict__ idx,
                   const float* __restrict__ emb,
                   float* __restrict__ z_q,
                   int* __restrict__ counts) {
    const int row  = blockIdx.x * 8 + (threadIdx.x >> 5);   // flat (b*S + s)
    const int lane = threadIdx.x & 31;
    const int k = idx[row];              // broadcast load (same addr across 32 lanes)
    const int s = row & (S_ - 1);        // S_ = 32 (power of 2)
    if (lane == 0) atomicAdd(&counts[s * K_ + k], 1);
    const float4* __restrict__ src =
        reinterpret_cast<const float4*>(emb + ((size_t)s * K_ + k) * D_);
    float4* __restrict__ dst =
        reinterpret_cast<float4*>(z_q + (size_t)row * D_);
    dst[lane] = src[lane];               // 512B gather read (L2/L3 hot), coalesced write
}

// Kernel 2: per-s new_ecs + n reduction + Laplace-smoothed cluster_size.
// One block (256 threads) per s; each thread owns 4 k's.
__global__ void __launch_bounds__(256)
ecs_kernel(const float* __restrict__ ecs_in,
           const int* __restrict__ counts,
           float* __restrict__ new_ecs_out,
           float* __restrict__ cs_out) {
    const int s = blockIdx.x;
    const int t = threadIdx.x;
    float v[4];
    float local = 0.0f;
#pragma unroll
    for (int i = 0; i < 4; ++i) {
        const int kk = i * 256 + t;
        const float ne = DECAY * ecs_in[s * K_ + kk]
                       + OMD * (float)counts[s * K_ + kk];
        v[i] = ne;
        local += ne;
        new_ecs_out[s * K_ + kk] = ne;
    }
    // block reduction: wave64 butterfly + 4-wave LDS combine
    __shared__ float red[4];
#pragma unroll
    for (int off = 1; off < 64; off <<= 1) local += __shfl_xor(local, off);
    if ((t & 63) == 0) red[t >> 6] = local;
    __syncthreads();
    const float n = red[0] + red[1] + red[2] + red[3];
    const float denom = n + (float)K_ * EPS;
#pragma unroll
    for (int i = 0; i < 4; ++i) {
        const int kk = i * 256 + t;
        cs_out[s * K_ + kk] = (v[i] + EPS) / denom * n;
    }
}

// Kernel 3: new_ema_w = decay*ema_w + (1-decay)*counts*emb ;
//           new_embedding = new_ema_w / cluster_size.
// One thread per float4 (S*K*D/4 = 1,048,576 float4s).
__global__ void __launch_bounds__(256)
ema_kernel(const float* __restrict__ ema_w,
           const float* __restrict__ emb,
           const int* __restrict__ counts,
           const float* __restrict__ cs,
           float* __restrict__ new_ema_w_out,
           float* __restrict__ new_emb_out) {
    const size_t e = (size_t)blockIdx.x * 256 + threadIdx.x;  // float4 index
    const int sk = (int)(e >> 5);                             // 32 float4 per (s,k)
    const float c   = (float)counts[sk];   // broadcast within 32-thread group
    const float csv = cs[sk];
    const float4 w  = reinterpret_cast<const float4*>(ema_w)[e];
    const float4 em = reinterpret_cast<const float4*>(emb)[e];
    float4 nw;
    nw.x = DECAY * w.x + OMD * c * em.x;
    nw.y = DECAY * w.y + OMD * c * em.y;
    nw.z = DECAY * w.z + OMD * c * em.z;
    nw.w = DECAY * w.w + OMD * c * em.w;
    reinterpret_cast<float4*>(new_ema_w_out)[e] = nw;
    float4 nb;
    nb.x = nw.x / csv;
    nb.y = nw.y / csv;
    nb.z = nw.z / csv;
    nb.w = nw.w / csv;
    reinterpret_cast<float4*>(new_emb_out)[e] = nb;
}

extern "C" void kernel_launch(void* const* d_in, const int* in_sizes, int n_in,
                              void* d_out, int out_size, void* d_ws, size_t ws_size,
                              hipStream_t stream) {
    const int*   idx   = (const int*)d_in[0];
    const float* emb   = (const float*)d_in[1];
    const float* ecs   = (const float*)d_in[2];
    const float* ema_w = (const float*)d_in[3];

    float* out       = (float*)d_out;
    float* z_q       = out;                                  // [B,S,D]
    float* new_emb   = z_q + (size_t)B_ * S_ * D_;           // [S,K,D]
    float* new_ecs   = new_emb + (size_t)S_ * K_ * D_;       // [S,K]
    float* new_ema_w = new_ecs + (size_t)S_ * K_;            // [S,K,D]

    int*   counts = (int*)d_ws;                              // S*K ints
    float* cs     = (float*)d_ws + (size_t)S_ * K_;          // S*K floats

    hipMemsetAsync(counts, 0, (size_t)S_ * K_ * sizeof(int), stream);

    gather_hist_kernel<<<(B_ * S_) / 8, 256, 0, stream>>>(idx, emb, z_q, counts);
    ecs_kernel<<<S_, 256, 0, stream>>>(ecs, counts, new_ecs, cs);
    ema_kernel<<<(S_ * K_ * D_ / 4) / 256, 256, 0, stream>>>(
        ema_w, emb, counts, cs, new_ema_w, new_emb);
}

// Round 3
// 39.172 us; speedup vs baseline: 1.0811x; 1.0811x over previous
//
#include <hip/hip_runtime.h>

// Problem constants
#define B_ 4096
#define S_ 32
#define K_ 1024
#define D_ 128
constexpr float DECAY = 0.99f;
constexpr float OMD   = 0.01f;     // 1 - decay
constexpr float EPS   = 1e-5f;

// Native clang vector types (work with __builtin_nontemporal_*)
typedef float f4 __attribute__((ext_vector_type(4)));
typedef int   i4 __attribute__((ext_vector_type(4)));

// ws layout: [0, S_*K_) int counts ; then S_ floats n[s]

// Kernel 0: zero the histogram AND compute n[s] in closed form.
// n[s] = sum_k new_ecs[s,k] = DECAY * rowsum(ecs_in[s,:]) + OMD * B
// (sum_k counts[s,k] == B exactly: each batch row contributes one index per s).
__global__ void __launch_bounds__(256)
init_kernel(const float* __restrict__ ecs_in,
            int* __restrict__ counts,
            float* __restrict__ n_out) {
    const int s = blockIdx.x;
    const int t = threadIdx.x;
    reinterpret_cast<i4*>(counts + s * K_)[t] = i4{0, 0, 0, 0};
    const f4 v = reinterpret_cast<const f4*>(ecs_in + s * K_)[t];
    float local = v.x + v.y + v.z + v.w;
#pragma unroll
    for (int off = 1; off < 64; off <<= 1) local += __shfl_xor(local, off);
    __shared__ float red[4];
    if ((t & 63) == 0) red[t >> 6] = local;
    __syncthreads();
    if (t == 0)
        n_out[s] = DECAY * (red[0] + red[1] + red[2] + red[3]) + OMD * (float)B_;
}

// Kernel 1: fused z_q gather + histogram.
// One (b,s) row handled by 32 threads (32 x float4 = 128 floats).
// z_q is write-once -> nontemporal store (don't evict embedding from L2).
__global__ void __launch_bounds__(256)
gather_hist_kernel(const int* __restrict__ idx,
                   const float* __restrict__ emb,
                   float* __restrict__ z_q,
                   int* __restrict__ counts) {
    const int row  = blockIdx.x * 8 + (threadIdx.x >> 5);   // flat (b*S + s)
    const int lane = threadIdx.x & 31;
    const int k = idx[row];              // broadcast load within 32-lane group
    const int s = row & (S_ - 1);        // S_ = 32
    if (lane == 0) atomicAdd(&counts[s * K_ + k], 1);
    const f4 val =
        reinterpret_cast<const f4*>(emb + ((size_t)s * K_ + k) * D_)[lane];
    __builtin_nontemporal_store(
        val, reinterpret_cast<f4*>(z_q + (size_t)row * D_) + lane);
}

// Kernel 2: fused EMA update + ecs + Laplace smoothing.
//   ne  = DECAY*ecs_in + OMD*counts            (scalar per (s,k), broadcast)
//   cs  = (ne+EPS)/(n+K*EPS)*n
//   nw  = DECAY*ema_w + OMD*counts*emb         (dw == counts*emb algebraically)
//   nb  = nw / cs
// One thread per float4; 32 threads share one (s,k).
__global__ void __launch_bounds__(256)
ema_kernel(const float* __restrict__ ema_w,
           const float* __restrict__ emb,
           const float* __restrict__ ecs_in,
           const int* __restrict__ counts,
           const float* __restrict__ n_arr,
           float* __restrict__ new_ecs_out,
           float* __restrict__ new_ema_w_out,
           float* __restrict__ new_emb_out) {
    const size_t e = (size_t)blockIdx.x * 256 + threadIdx.x;  // float4 index
    const int sk = (int)(e >> 5);                             // 32 float4 per (s,k)
    const int s  = sk >> 10;                                  // K_ = 1024
    const float c  = (float)counts[sk];
    const float ne = DECAY * ecs_in[sk] + OMD * c;
    const float n  = n_arr[s];
    const float cs = (ne + EPS) / (n + (float)K_ * EPS) * n;
    if ((e & 31) == 0) new_ecs_out[sk] = ne;

    const f4 w =
        __builtin_nontemporal_load(reinterpret_cast<const f4*>(ema_w) + e);
    const f4 em = reinterpret_cast<const f4*>(emb)[e];
    f4 nw;
    nw.x = DECAY * w.x + OMD * c * em.x;
    nw.y = DECAY * w.y + OMD * c * em.y;
    nw.z = DECAY * w.z + OMD * c * em.z;
    nw.w = DECAY * w.w + OMD * c * em.w;
    __builtin_nontemporal_store(
        nw, reinterpret_cast<f4*>(new_ema_w_out) + e);
    const float inv = 1.0f / cs;
    f4 nb;
    nb.x = nw.x * inv;
    nb.y = nw.y * inv;
    nb.z = nw.z * inv;
    nb.w = nw.w * inv;
    __builtin_nontemporal_store(
        nb, reinterpret_cast<f4*>(new_emb_out) + e);
}

extern "C" void kernel_launch(void* const* d_in, const int* in_sizes, int n_in,
                              void* d_out, int out_size, void* d_ws, size_t ws_size,
                              hipStream_t stream) {
    const int*   idx   = (const int*)d_in[0];
    const float* emb   = (const float*)d_in[1];
    const float* ecs   = (const float*)d_in[2];
    const float* ema_w = (const float*)d_in[3];

    float* out       = (float*)d_out;
    float* z_q       = out;                                  // [B,S,D]
    float* new_emb   = z_q + (size_t)B_ * S_ * D_;           // [S,K,D]
    float* new_ecs   = new_emb + (size_t)S_ * K_ * D_;       // [S,K]
    float* new_ema_w = new_ecs + (size_t)S_ * K_;            // [S,K,D]

    int*   counts = (int*)d_ws;                              // S*K ints
    float* n_arr  = (float*)d_ws + (size_t)S_ * K_;          // S floats

    init_kernel<<<S_, 256, 0, stream>>>(ecs, counts, n_arr);
    gather_hist_kernel<<<(B_ * S_) / 8, 256, 0, stream>>>(idx, emb, z_q, counts);
    ema_kernel<<<(S_ * K_ * D_ / 4) / 256, 256, 0, stream>>>(
        ema_w, emb, ecs, counts, n_arr, new_ecs, new_ema_w, new_emb);
}